// Round 3
// baseline (3148.039 us; speedup 1.0000x reference)
//
#include <hip/hip_runtime.h>

typedef _Float16 half8 __attribute__((ext_vector_type(8)));
typedef unsigned short ushort8 __attribute__((ext_vector_type(8)));
typedef float floatx4 __attribute__((ext_vector_type(4)));
typedef unsigned short u16;

#define NROWS 115200
#define MT 32

__device__ __forceinline__ void splitf(float f, u16& hi, u16& lo) {
    _Float16 h = (_Float16)f;
    _Float16 l = (_Float16)(f - (float)h);
    hi = __builtin_bit_cast(u16, h);
    lo = __builtin_bit_cast(u16, l);
}

// swizzled index into a [MT][256] fp16 LDS plane (16B-block XOR swizzle)
__device__ __forceinline__ int swz(int row, int col) {
    return row * 256 + ((((col >> 3)) ^ (row & 31)) << 3) + (col & 7);
}

// dst_{hi,lo}[n][k] = split fp16 of src[k][n], zero-padded to [Nd][Kd]
__global__ void prep_transpose(const float* __restrict__ src, u16* __restrict__ dhi,
                               u16* __restrict__ dlo, int K, int N, int Kd) {
    __shared__ float tile[32][33];
    int ktiles = Kd >> 5;
    int bk = blockIdx.x % ktiles, bn = blockIdx.x / ktiles;
    int k0 = bk << 5, n0 = bn << 5;
    int tx = threadIdx.x & 31, ty = threadIdx.x >> 5;  // 32x8
    for (int i = 0; i < 32; i += 8) {
        int k = k0 + ty + i, n = n0 + tx;
        tile[ty + i][tx] = (k < K && n < N) ? src[(size_t)k * N + n] : 0.f;
    }
    __syncthreads();
    for (int i = 0; i < 32; i += 8) {
        int n = n0 + ty + i, k = k0 + tx;
        u16 hi, lo;
        splitf(tile[tx][ty + i], hi, lo);
        dhi[(size_t)n * Kd + k] = hi;
        dlo[(size_t)n * Kd + k] = lo;
    }
}

__global__ __launch_bounds__(256, 2) void fused_head(
    const float* __restrict__ xg,
    const u16* __restrict__ w1h, const u16* __restrict__ w1l,
    const u16* __restrict__ w2h, const u16* __restrict__ w2l,
    const u16* __restrict__ w3h, const u16* __restrict__ w3l,
    const float* __restrict__ b1g, const float* __restrict__ b2g, const float* __restrict__ b3g,
    const float* __restrict__ ipose, const float* __restrict__ ishape, const float* __restrict__ icam,
    float* __restrict__ out)
{
    __shared__ __align__(16) u16 smem[4 * MT * 256];
    u16* xsh = smem;                  // x hi plane
    u16* xsl = smem + MT * 256;       // x lo plane
    u16* hsh = smem + 2 * MT * 256;   // h / theta hi plane
    u16* hsl = smem + 3 * MT * 256;   // h / theta lo plane
    float* thf = (float*)smem;        // [MT][144] fp32 pose (epilogue only; overlays x planes)

    const int t = threadIdx.x;
    const int lid = t & 63, wv = t >> 6;       // 4 waves
    const int q = lid >> 4, m = lid & 15;      // quad, lane-in-16
    const long rowbase = (long)blockIdx.x * MT;

    // ---- stage x tile (32 rows x 256 fp32 -> split fp16 planes) ----
    #pragma unroll
    for (int i = 0; i < 4; ++i) {
        int idx = t + i * 256;
        int r = idx >> 5, s = idx & 31;
        const float4* sp = (const float4*)(xg + (rowbase + r) * 256 + s * 8);
        float4 f0 = sp[0], f1 = sp[1];
        float fv[8] = {f0.x, f0.y, f0.z, f0.w, f1.x, f1.y, f1.z, f1.w};
        ushort8 vh, vl;
        #pragma unroll
        for (int j = 0; j < 8; ++j) {
            u16 hi, lo; splitf(fv[j], hi, lo);
            vh[j] = hi; vl[j] = lo;
        }
        int o = r * 256 + ((s ^ (r & 31)) << 3);
        *(ushort8*)&xsh[o] = vh;
        *(ushort8*)&xsl[o] = vl;
    }

    // ---- theta fp32 master in registers (GEMM3 C-frag layout) ----
    const int ncts = (wv < 2) ? 3 : 2;
    float tm[3][2][4];
    #pragma unroll
    for (int c = 0; c < 3; ++c) {
        int n3 = (wv + c * 4) * 16 + m;
        float v;
        if (n3 < 144)      v = ipose[n3];
        else if (n3 < 154) v = ishape[n3 - 144];
        else if (n3 < 157) v = icam[n3 - 154];
        else               v = 0.f;
        #pragma unroll
        for (int rt = 0; rt < 2; ++rt)
            #pragma unroll
            for (int r = 0; r < 4; ++r) tm[c][rt][r] = v;
    }
    // theta split-fp16 staging for GEMM1 A-operand (rows stride 168 in h planes)
    #pragma unroll
    for (int c = 0; c < 3; ++c) {
        if (c < ncts) {
            int n3 = (wv + c * 4) * 16 + m;
            #pragma unroll
            for (int rt = 0; rt < 2; ++rt)
                #pragma unroll
                for (int r = 0; r < 4; ++r) {
                    int row = rt * 16 + q * 4 + r;
                    u16 hi, lo; splitf(tm[c][rt][r], hi, lo);
                    hsh[row * 168 + n3] = hi;
                    hsl[row * 168 + n3] = lo;
                }
        }
    }
    __syncthreads();

    const floatx4 zero4 = {0.f, 0.f, 0.f, 0.f};

    for (int it = 0; it < 3; ++it) {
        // ============ GEMM1: h1 = relu([x|theta] @ W1 + b1), K=416 ============
        floatx4 acc[4][2];
        #pragma unroll
        for (int ct = 0; ct < 4; ++ct)
            #pragma unroll
            for (int rt = 0; rt < 2; ++rt) acc[ct][rt] = zero4;

        #pragma unroll
        for (int ks = 0; ks < 13; ++ks) {
            int kk = ks * 32 + q * 8;
            half8 ah[2], al[2];
            if (ks < 8) {
                #pragma unroll
                for (int rt = 0; rt < 2; ++rt) {
                    int o = swz(rt * 16 + m, kk);
                    ah[rt] = *(const half8*)&xsh[o];
                    al[rt] = *(const half8*)&xsl[o];
                }
            } else {
                int kp = kk - 256;
                #pragma unroll
                for (int rt = 0; rt < 2; ++rt) {
                    int o = (rt * 16 + m) * 168 + kp;
                    ah[rt] = *(const half8*)&hsh[o];
                    al[rt] = *(const half8*)&hsl[o];
                }
            }
            #pragma unroll
            for (int ct = 0; ct < 4; ++ct) {
                int n = wv * 64 + ct * 16 + m;
                half8 bh = *(const half8*)(w1h + n * 416 + kk);
                half8 bl = *(const half8*)(w1l + n * 416 + kk);
                #pragma unroll
                for (int rt = 0; rt < 2; ++rt) {
                    acc[ct][rt] = __builtin_amdgcn_mfma_f32_16x16x32_f16(ah[rt], bh, acc[ct][rt], 0, 0, 0);
                    acc[ct][rt] = __builtin_amdgcn_mfma_f32_16x16x32_f16(al[rt], bh, acc[ct][rt], 0, 0, 0);
                    acc[ct][rt] = __builtin_amdgcn_mfma_f32_16x16x32_f16(ah[rt], bl, acc[ct][rt], 0, 0, 0);
                }
            }
        }
        __syncthreads();
        #pragma unroll
        for (int ct = 0; ct < 4; ++ct) {
            int n = wv * 64 + ct * 16 + m;
            float bv = b1g[n];
            #pragma unroll
            for (int rt = 0; rt < 2; ++rt)
                #pragma unroll
                for (int r = 0; r < 4; ++r) {
                    int row = rt * 16 + q * 4 + r;
                    float v = fmaxf(acc[ct][rt][r] + bv, 0.f);
                    u16 hi, lo; splitf(v, hi, lo);
                    int o = swz(row, n);
                    hsh[o] = hi; hsl[o] = lo;
                }
        }
        __syncthreads();

        // ============ GEMM2: h2 = h1 @ W2 + b2, K=256 ============
        #pragma unroll
        for (int ct = 0; ct < 4; ++ct)
            #pragma unroll
            for (int rt = 0; rt < 2; ++rt) acc[ct][rt] = zero4;

        #pragma unroll
        for (int ks = 0; ks < 8; ++ks) {
            int kk = ks * 32 + q * 8;
            half8 ah[2], al[2];
            #pragma unroll
            for (int rt = 0; rt < 2; ++rt) {
                int o = swz(rt * 16 + m, kk);
                ah[rt] = *(const half8*)&hsh[o];
                al[rt] = *(const half8*)&hsl[o];
            }
            #pragma unroll
            for (int ct = 0; ct < 4; ++ct) {
                int n = wv * 64 + ct * 16 + m;
                half8 bh = *(const half8*)(w2h + n * 256 + kk);
                half8 bl = *(const half8*)(w2l + n * 256 + kk);
                #pragma unroll
                for (int rt = 0; rt < 2; ++rt) {
                    acc[ct][rt] = __builtin_amdgcn_mfma_f32_16x16x32_f16(ah[rt], bh, acc[ct][rt], 0, 0, 0);
                    acc[ct][rt] = __builtin_amdgcn_mfma_f32_16x16x32_f16(al[rt], bh, acc[ct][rt], 0, 0, 0);
                    acc[ct][rt] = __builtin_amdgcn_mfma_f32_16x16x32_f16(ah[rt], bl, acc[ct][rt], 0, 0, 0);
                }
            }
        }
        __syncthreads();
        #pragma unroll
        for (int ct = 0; ct < 4; ++ct) {
            int n = wv * 64 + ct * 16 + m;
            float bv = b2g[n];
            #pragma unroll
            for (int rt = 0; rt < 2; ++rt)
                #pragma unroll
                for (int r = 0; r < 4; ++r) {
                    int row = rt * 16 + q * 4 + r;
                    float v = acc[ct][rt][r] + bv;
                    u16 hi, lo; splitf(v, hi, lo);
                    int o = swz(row, n);
                    hsh[o] = hi; hsl[o] = lo;
                }
        }
        __syncthreads();

        // ============ GEMM3: theta += h2 @ W3 + b3, K=256, N=160(pad) ============
        floatx4 a3[3][2];
        #pragma unroll
        for (int c = 0; c < 3; ++c)
            #pragma unroll
            for (int rt = 0; rt < 2; ++rt) a3[c][rt] = zero4;

        #pragma unroll
        for (int ks = 0; ks < 8; ++ks) {
            int kk = ks * 32 + q * 8;
            half8 ah[2], al[2];
            #pragma unroll
            for (int rt = 0; rt < 2; ++rt) {
                int o = swz(rt * 16 + m, kk);
                ah[rt] = *(const half8*)&hsh[o];
                al[rt] = *(const half8*)&hsl[o];
            }
            #pragma unroll
            for (int c = 0; c < 3; ++c) {
                if (c < ncts) {
                    int n3 = (wv + c * 4) * 16 + m;
                    half8 bh = *(const half8*)(w3h + n3 * 256 + kk);
                    half8 bl = *(const half8*)(w3l + n3 * 256 + kk);
                    #pragma unroll
                    for (int rt = 0; rt < 2; ++rt) {
                        a3[c][rt] = __builtin_amdgcn_mfma_f32_16x16x32_f16(ah[rt], bh, a3[c][rt], 0, 0, 0);
                        a3[c][rt] = __builtin_amdgcn_mfma_f32_16x16x32_f16(al[rt], bh, a3[c][rt], 0, 0, 0);
                        a3[c][rt] = __builtin_amdgcn_mfma_f32_16x16x32_f16(ah[rt], bl, a3[c][rt], 0, 0, 0);
                    }
                }
            }
        }
        // fp32 residual update of theta master
        #pragma unroll
        for (int c = 0; c < 3; ++c) {
            if (c < ncts) {
                int n3 = (wv + c * 4) * 16 + m;
                float b3v = (n3 < 157) ? b3g[n3] : 0.f;
                #pragma unroll
                for (int rt = 0; rt < 2; ++rt)
                    #pragma unroll
                    for (int r = 0; r < 4; ++r)
                        tm[c][rt][r] += a3[c][rt][r] + b3v;
            }
        }
        __syncthreads();   // all GEMM3 reads of h2 done; x planes also long dead this iter

        if (it < 2) {
            // re-stage theta split-fp16 for next GEMM1
            #pragma unroll
            for (int c = 0; c < 3; ++c) {
                if (c < ncts) {
                    int n3 = (wv + c * 4) * 16 + m;
                    #pragma unroll
                    for (int rt = 0; rt < 2; ++rt)
                        #pragma unroll
                        for (int r = 0; r < 4; ++r) {
                            int row = rt * 16 + q * 4 + r;
                            u16 hi, lo; splitf(tm[c][rt][r], hi, lo);
                            hsh[row * 168 + n3] = hi;
                            hsl[row * 168 + n3] = lo;
                        }
                }
            }
        } else {
            // final: pose -> fp32 LDS (overlay x planes); betas/camera -> global fp32
            #pragma unroll
            for (int c = 0; c < 3; ++c) {
                if (c < ncts) {
                    int tile = wv + c * 4;
                    int n3 = tile * 16 + m;
                    if (tile < 9) {
                        #pragma unroll
                        for (int rt = 0; rt < 2; ++rt)
                            #pragma unroll
                            for (int r = 0; r < 4; ++r) {
                                int row = rt * 16 + q * 4 + r;
                                thf[row * 144 + n3] = tm[c][rt][r];
                            }
                    } else {  // tile 9: cols 144..159 = betas + camera
                        #pragma unroll
                        for (int rt = 0; rt < 2; ++rt)
                            #pragma unroll
                            for (int r = 0; r < 4; ++r) {
                                int row = rt * 16 + q * 4 + r;
                                long grow = rowbase + row;
                                float v = tm[c][rt][r];
                                if (m < 10)
                                    out[(size_t)NROWS * 216 + grow * 10 + m] = v;
                                else if (m < 13)
                                    out[(size_t)NROWS * 216 + (size_t)NROWS * 10 + grow * 3 + (m - 10)] = v;
                            }
                    }
                }
            }
        }
        __syncthreads();
    }

    // ============ epilogue: rot6d -> rotmat (fp32) ============
    {
        int r = t >> 3, g = t & 7;     // 8 threads per row, 3 joints each
        long grow = rowbase + r;
        #pragma unroll
        for (int jj = 0; jj < 3; ++jj) {
            int j = g * 3 + jj;
            const float* p = &thf[r * 144 + j * 6];
            float a1x = p[0], a2x = p[1], a1y = p[2], a2y = p[3], a1z = p[4], a2z = p[5];
            float n1 = fmaxf(sqrtf(a1x * a1x + a1y * a1y + a1z * a1z), 1e-12f);
            float b1x = a1x / n1, b1y = a1y / n1, b1z = a1z / n1;
            float d = b1x * a2x + b1y * a2y + b1z * a2z;
            float ux = a2x - d * b1x, uy = a2y - d * b1y, uz = a2z - d * b1z;
            float n2 = fmaxf(sqrtf(ux * ux + uy * uy + uz * uz), 1e-12f);
            float b2x = ux / n2, b2y = uy / n2, b2z = uz / n2;
            float b3x = b1y * b2z - b1z * b2y;
            float b3y = b1z * b2x - b1x * b2z;
            float b3z = b1x * b2y - b1y * b2x;
            float* o = out + (size_t)grow * 216 + j * 9;
            o[0] = b1x; o[1] = b2x; o[2] = b3x;
            o[3] = b1y; o[4] = b2y; o[5] = b3y;
            o[6] = b1z; o[7] = b2z; o[8] = b3z;
        }
    }
}

extern "C" void kernel_launch(void* const* d_in, const int* in_sizes, int n_in,
                              void* d_out, int out_size, void* d_ws, size_t ws_size,
                              hipStream_t stream) {
    const float* x  = (const float*)d_in[0];
    // d_in[1] = pred_class (unused by reference)
    const float* W1 = (const float*)d_in[2];
    const float* b1 = (const float*)d_in[3];
    const float* W2 = (const float*)d_in[4];
    const float* b2 = (const float*)d_in[5];
    const float* W3 = (const float*)d_in[6];
    const float* b3 = (const float*)d_in[7];
    const float* ip = (const float*)d_in[8];
    const float* is = (const float*)d_in[9];
    const float* ic = (const float*)d_in[10];

    u16* w1h = (u16*)d_ws;            // [256][416] hi
    u16* w1l = w1h + 256 * 416;       // [256][416] lo
    u16* w2h = w1l + 256 * 416;       // [256][256] hi
    u16* w2l = w2h + 256 * 256;       // [256][256] lo
    u16* w3h = w2l + 256 * 256;       // [160][256] hi
    u16* w3l = w3h + 160 * 256;       // [160][256] lo

    prep_transpose<<<13 * 8, 256, 0, stream>>>(W1, w1h, w1l, 413, 256, 416);
    prep_transpose<<<8 * 8, 256, 0, stream>>>(W2, w2h, w2l, 256, 256, 256);
    prep_transpose<<<8 * 5, 256, 0, stream>>>(W3, w3h, w3l, 256, 157, 256);

    fused_head<<<NROWS / MT, 256, 0, stream>>>(x, w1h, w1l, w2h, w2l, w3h, w3l,
                                               b1, b2, b3, ip, is, ic, (float*)d_out);
}

// Round 4
// 750.414 us; speedup vs baseline: 4.1951x; 4.1951x over previous
//
#include <hip/hip_runtime.h>

typedef _Float16 half8 __attribute__((ext_vector_type(8)));
typedef unsigned short ushort8 __attribute__((ext_vector_type(8)));
typedef float floatx4 __attribute__((ext_vector_type(4)));
typedef unsigned short u16;

#define NROWS 115200
#define MT 32

__device__ __forceinline__ void splitf(float f, u16& hi, u16& lo) {
    _Float16 h = (_Float16)f;
    _Float16 l = (_Float16)(f - (float)h);
    hi = __builtin_bit_cast(u16, h);
    lo = __builtin_bit_cast(u16, l);
}

// swizzled index into a [MT][256] fp16 LDS plane (16B-block XOR swizzle)
__device__ __forceinline__ int swz(int row, int col) {
    return row * 256 + ((((col >> 3)) ^ (row & 31)) << 3) + (col & 7);
}

// Pack src[K][N] fp32 into fragment-major split-fp16 planes:
// dst[((nt*kfrags + kf)*16 + m)*8 + j] = src[kf*8+j][nt*16+m]
// so a wave's (q,m) fragment load for (ntile, ks) is 1024 B dense.
__global__ void prep_pack(const float* __restrict__ src, u16* __restrict__ dhi,
                          u16* __restrict__ dlo, int K, int N, int Kd) {
    int kfrags = Kd >> 3;
    int nt = blockIdx.y;
    int frag = blockIdx.x * blockDim.x + threadIdx.x;
    if (frag >= kfrags * 16) return;
    int kf = frag >> 4, m = frag & 15;
    int n = nt * 16 + m;
    ushort8 vh, vl;
    #pragma unroll
    for (int j = 0; j < 8; ++j) {
        int k = kf * 8 + j;
        float v = (k < K && n < N) ? src[(size_t)k * N + n] : 0.f;
        u16 hi, lo; splitf(v, hi, lo);
        vh[j] = hi; vl[j] = lo;
    }
    size_t o = ((size_t)nt * kfrags + kf) * 128 + (size_t)m * 8;
    *(ushort8*)&dhi[o] = vh;
    *(ushort8*)&dlo[o] = vl;
}

__global__ __launch_bounds__(256, 2) void fused_head(
    const float* __restrict__ xg,
    const u16* __restrict__ w1h, const u16* __restrict__ w1l,
    const u16* __restrict__ w2h, const u16* __restrict__ w2l,
    const u16* __restrict__ w3h, const u16* __restrict__ w3l,
    const float* __restrict__ b1g, const float* __restrict__ b2g, const float* __restrict__ b3g,
    const float* __restrict__ ipose, const float* __restrict__ ishape, const float* __restrict__ icam,
    float* __restrict__ out)
{
    __shared__ __align__(16) u16 smem[4 * MT * 256];
    u16* xsh = smem;                  // x hi plane
    u16* xsl = smem + MT * 256;       // x lo plane
    u16* hsh = smem + 2 * MT * 256;   // h / theta hi plane
    u16* hsl = smem + 3 * MT * 256;   // h / theta lo plane
    float* thf = (float*)smem;        // [MT][144] fp32 pose (epilogue only; overlays x planes)

    const int t = threadIdx.x;
    const int lid = t & 63, wv = t >> 6;       // 4 waves
    const int q = lid >> 4, m = lid & 15;      // quad, lane-in-16
    const int fb = q * 128 + m * 8;            // fragment-local B offset
    const long rowbase = (long)blockIdx.x * MT;

    // ---- stage x tile (32 rows x 256 fp32 -> split fp16 planes) ----
    #pragma unroll
    for (int i = 0; i < 4; ++i) {
        int idx = t + i * 256;
        int r = idx >> 5, s = idx & 31;
        const float4* sp = (const float4*)(xg + (rowbase + r) * 256 + s * 8);
        float4 f0 = sp[0], f1 = sp[1];
        float fv[8] = {f0.x, f0.y, f0.z, f0.w, f1.x, f1.y, f1.z, f1.w};
        ushort8 vh, vl;
        #pragma unroll
        for (int j = 0; j < 8; ++j) {
            u16 hi, lo; splitf(fv[j], hi, lo);
            vh[j] = hi; vl[j] = lo;
        }
        int o = r * 256 + ((s ^ (r & 31)) << 3);
        *(ushort8*)&xsh[o] = vh;
        *(ushort8*)&xsl[o] = vl;
    }

    // ---- theta fp32 master in registers (GEMM3 C-frag layout) ----
    const int ncts = (wv < 2) ? 3 : 2;
    float tm[3][2][4];
    #pragma unroll
    for (int c = 0; c < 3; ++c) {
        int n3 = (wv + c * 4) * 16 + m;
        float v;
        if (n3 < 144)      v = ipose[n3];
        else if (n3 < 154) v = ishape[n3 - 144];
        else if (n3 < 157) v = icam[n3 - 154];
        else               v = 0.f;
        #pragma unroll
        for (int rt = 0; rt < 2; ++rt)
            #pragma unroll
            for (int r = 0; r < 4; ++r) tm[c][rt][r] = v;
    }
    #pragma unroll
    for (int c = 0; c < 3; ++c) {
        if (c < ncts) {
            int n3 = (wv + c * 4) * 16 + m;
            #pragma unroll
            for (int rt = 0; rt < 2; ++rt)
                #pragma unroll
                for (int r = 0; r < 4; ++r) {
                    int row = rt * 16 + q * 4 + r;
                    u16 hi, lo; splitf(tm[c][rt][r], hi, lo);
                    hsh[row * 168 + n3] = hi;
                    hsl[row * 168 + n3] = lo;
                }
        }
    }
    __syncthreads();

    const floatx4 zero4 = {0.f, 0.f, 0.f, 0.f};

    for (int it = 0; it < 3; ++it) {
        // ============ GEMM1: h1 = relu([x|theta] @ W1 + b1), K=416 ============
        floatx4 acc[4][2];
        #pragma unroll
        for (int ct = 0; ct < 4; ++ct)
            #pragma unroll
            for (int rt = 0; rt < 2; ++rt) acc[ct][rt] = zero4;

        #pragma unroll 2
        for (int ks = 0; ks < 8; ++ks) {
            half8 ah[2], al[2];
            #pragma unroll
            for (int rt = 0; rt < 2; ++rt) {
                int o = swz(rt * 16 + m, ks * 32 + q * 8);
                ah[rt] = *(const half8*)&xsh[o];
                al[rt] = *(const half8*)&xsl[o];
            }
            int bbase = wv * 26624 + ks * 512 + fb;
            #pragma unroll
            for (int ct = 0; ct < 4; ++ct) {
                half8 bh = *(const half8*)(w1h + bbase + ct * 6656);
                half8 bl = *(const half8*)(w1l + bbase + ct * 6656);
                #pragma unroll
                for (int rt = 0; rt < 2; ++rt) {
                    acc[ct][rt] = __builtin_amdgcn_mfma_f32_16x16x32_f16(ah[rt], bh, acc[ct][rt], 0, 0, 0);
                    acc[ct][rt] = __builtin_amdgcn_mfma_f32_16x16x32_f16(al[rt], bh, acc[ct][rt], 0, 0, 0);
                    acc[ct][rt] = __builtin_amdgcn_mfma_f32_16x16x32_f16(ah[rt], bl, acc[ct][rt], 0, 0, 0);
                }
            }
        }
        #pragma unroll 1
        for (int ks = 8; ks < 13; ++ks) {
            int kp = (ks - 8) * 32 + q * 8;
            half8 ah[2], al[2];
            #pragma unroll
            for (int rt = 0; rt < 2; ++rt) {
                int o = (rt * 16 + m) * 168 + kp;
                ah[rt] = *(const half8*)&hsh[o];
                al[rt] = *(const half8*)&hsl[o];
            }
            int bbase = wv * 26624 + ks * 512 + fb;
            #pragma unroll
            for (int ct = 0; ct < 4; ++ct) {
                half8 bh = *(const half8*)(w1h + bbase + ct * 6656);
                half8 bl = *(const half8*)(w1l + bbase + ct * 6656);
                #pragma unroll
                for (int rt = 0; rt < 2; ++rt) {
                    acc[ct][rt] = __builtin_amdgcn_mfma_f32_16x16x32_f16(ah[rt], bh, acc[ct][rt], 0, 0, 0);
                    acc[ct][rt] = __builtin_amdgcn_mfma_f32_16x16x32_f16(al[rt], bh, acc[ct][rt], 0, 0, 0);
                    acc[ct][rt] = __builtin_amdgcn_mfma_f32_16x16x32_f16(ah[rt], bl, acc[ct][rt], 0, 0, 0);
                }
            }
        }
        __syncthreads();
        #pragma unroll
        for (int ct = 0; ct < 4; ++ct) {
            int n = wv * 64 + ct * 16 + m;
            float bv = b1g[n];
            #pragma unroll
            for (int rt = 0; rt < 2; ++rt)
                #pragma unroll
                for (int r = 0; r < 4; ++r) {
                    int row = rt * 16 + q * 4 + r;
                    float v = fmaxf(acc[ct][rt][r] + bv, 0.f);
                    u16 hi, lo; splitf(v, hi, lo);
                    int o = swz(row, n);
                    hsh[o] = hi; hsl[o] = lo;
                }
        }
        __syncthreads();

        // ============ GEMM2: h2 = h1 @ W2 + b2, K=256 ============
        #pragma unroll
        for (int ct = 0; ct < 4; ++ct)
            #pragma unroll
            for (int rt = 0; rt < 2; ++rt) acc[ct][rt] = zero4;

        #pragma unroll 2
        for (int ks = 0; ks < 8; ++ks) {
            half8 ah[2], al[2];
            #pragma unroll
            for (int rt = 0; rt < 2; ++rt) {
                int o = swz(rt * 16 + m, ks * 32 + q * 8);
                ah[rt] = *(const half8*)&hsh[o];
                al[rt] = *(const half8*)&hsl[o];
            }
            int bbase = wv * 16384 + ks * 512 + fb;
            #pragma unroll
            for (int ct = 0; ct < 4; ++ct) {
                half8 bh = *(const half8*)(w2h + bbase + ct * 4096);
                half8 bl = *(const half8*)(w2l + bbase + ct * 4096);
                #pragma unroll
                for (int rt = 0; rt < 2; ++rt) {
                    acc[ct][rt] = __builtin_amdgcn_mfma_f32_16x16x32_f16(ah[rt], bh, acc[ct][rt], 0, 0, 0);
                    acc[ct][rt] = __builtin_amdgcn_mfma_f32_16x16x32_f16(al[rt], bh, acc[ct][rt], 0, 0, 0);
                    acc[ct][rt] = __builtin_amdgcn_mfma_f32_16x16x32_f16(ah[rt], bl, acc[ct][rt], 0, 0, 0);
                }
            }
        }
        __syncthreads();
        #pragma unroll
        for (int ct = 0; ct < 4; ++ct) {
            int n = wv * 64 + ct * 16 + m;
            float bv = b2g[n];
            #pragma unroll
            for (int rt = 0; rt < 2; ++rt)
                #pragma unroll
                for (int r = 0; r < 4; ++r) {
                    int row = rt * 16 + q * 4 + r;
                    float v = acc[ct][rt][r] + bv;
                    u16 hi, lo; splitf(v, hi, lo);
                    int o = swz(row, n);
                    hsh[o] = hi; hsl[o] = lo;
                }
        }
        __syncthreads();

        // ============ GEMM3: theta += h2 @ W3 + b3, K=256, N=160(pad) ============
        floatx4 a3[3][2];
        #pragma unroll
        for (int c = 0; c < 3; ++c)
            #pragma unroll
            for (int rt = 0; rt < 2; ++rt) a3[c][rt] = zero4;

        #pragma unroll 2
        for (int ks = 0; ks < 8; ++ks) {
            half8 ah[2], al[2];
            #pragma unroll
            for (int rt = 0; rt < 2; ++rt) {
                int o = swz(rt * 16 + m, ks * 32 + q * 8);
                ah[rt] = *(const half8*)&hsh[o];
                al[rt] = *(const half8*)&hsl[o];
            }
            int bbase = ks * 512 + fb;
            #pragma unroll
            for (int c = 0; c < 3; ++c) {
                if (c < ncts) {
                    half8 bh = *(const half8*)(w3h + bbase + (wv + c * 4) * 4096);
                    half8 bl = *(const half8*)(w3l + bbase + (wv + c * 4) * 4096);
                    #pragma unroll
                    for (int rt = 0; rt < 2; ++rt) {
                        a3[c][rt] = __builtin_amdgcn_mfma_f32_16x16x32_f16(ah[rt], bh, a3[c][rt], 0, 0, 0);
                        a3[c][rt] = __builtin_amdgcn_mfma_f32_16x16x32_f16(al[rt], bh, a3[c][rt], 0, 0, 0);
                        a3[c][rt] = __builtin_amdgcn_mfma_f32_16x16x32_f16(ah[rt], bl, a3[c][rt], 0, 0, 0);
                    }
                }
            }
        }
        // fp32 residual update of theta master
        #pragma unroll
        for (int c = 0; c < 3; ++c) {
            if (c < ncts) {
                int n3 = (wv + c * 4) * 16 + m;
                float b3v = (n3 < 157) ? b3g[n3] : 0.f;
                #pragma unroll
                for (int rt = 0; rt < 2; ++rt)
                    #pragma unroll
                    for (int r = 0; r < 4; ++r)
                        tm[c][rt][r] += a3[c][rt][r] + b3v;
            }
        }
        __syncthreads();   // all GEMM3 reads of h2 done

        if (it < 2) {
            // re-stage theta split-fp16 for next GEMM1
            #pragma unroll
            for (int c = 0; c < 3; ++c) {
                if (c < ncts) {
                    int n3 = (wv + c * 4) * 16 + m;
                    #pragma unroll
                    for (int rt = 0; rt < 2; ++rt)
                        #pragma unroll
                        for (int r = 0; r < 4; ++r) {
                            int row = rt * 16 + q * 4 + r;
                            u16 hi, lo; splitf(tm[c][rt][r], hi, lo);
                            hsh[row * 168 + n3] = hi;
                            hsl[row * 168 + n3] = lo;
                        }
                }
            }
        } else {
            // final: pose -> fp32 LDS (overlay x planes); betas/camera -> global fp32
            #pragma unroll
            for (int c = 0; c < 3; ++c) {
                if (c < ncts) {
                    int tile = wv + c * 4;
                    int n3 = tile * 16 + m;
                    if (tile < 9) {
                        #pragma unroll
                        for (int rt = 0; rt < 2; ++rt)
                            #pragma unroll
                            for (int r = 0; r < 4; ++r) {
                                int row = rt * 16 + q * 4 + r;
                                thf[row * 144 + n3] = tm[c][rt][r];
                            }
                    } else {  // tile 9: cols 144..159 = betas + camera
                        #pragma unroll
                        for (int rt = 0; rt < 2; ++rt)
                            #pragma unroll
                            for (int r = 0; r < 4; ++r) {
                                int row = rt * 16 + q * 4 + r;
                                long grow = rowbase + row;
                                float v = tm[c][rt][r];
                                if (m < 10)
                                    out[(size_t)NROWS * 216 + grow * 10 + m] = v;
                                else if (m < 13)
                                    out[(size_t)NROWS * 216 + (size_t)NROWS * 10 + grow * 3 + (m - 10)] = v;
                            }
                    }
                }
            }
        }
        __syncthreads();
    }

    // ============ epilogue: rot6d -> rotmat (fp32) ============
    {
        int r = t >> 3, g = t & 7;     // 8 threads per row, 3 joints each
        long grow = rowbase + r;
        #pragma unroll
        for (int jj = 0; jj < 3; ++jj) {
            int j = g * 3 + jj;
            const float* p = &thf[r * 144 + j * 6];
            float a1x = p[0], a2x = p[1], a1y = p[2], a2y = p[3], a1z = p[4], a2z = p[5];
            float n1 = fmaxf(sqrtf(a1x * a1x + a1y * a1y + a1z * a1z), 1e-12f);
            float b1x = a1x / n1, b1y = a1y / n1, b1z = a1z / n1;
            float d = b1x * a2x + b1y * a2y + b1z * a2z;
            float ux = a2x - d * b1x, uy = a2y - d * b1y, uz = a2z - d * b1z;
            float n2 = fmaxf(sqrtf(ux * ux + uy * uy + uz * uz), 1e-12f);
            float b2x = ux / n2, b2y = uy / n2, b2z = uz / n2;
            float b3x = b1y * b2z - b1z * b2y;
            float b3y = b1z * b2x - b1x * b2z;
            float b3z = b1x * b2y - b1y * b2x;
            float* o = out + (size_t)grow * 216 + j * 9;
            o[0] = b1x; o[1] = b2x; o[2] = b3x;
            o[3] = b1y; o[4] = b2y; o[5] = b3y;
            o[6] = b1z; o[7] = b2z; o[8] = b3z;
        }
    }
}

extern "C" void kernel_launch(void* const* d_in, const int* in_sizes, int n_in,
                              void* d_out, int out_size, void* d_ws, size_t ws_size,
                              hipStream_t stream) {
    const float* x  = (const float*)d_in[0];
    const float* W1 = (const float*)d_in[2];
    const float* b1 = (const float*)d_in[3];
    const float* W2 = (const float*)d_in[4];
    const float* b2 = (const float*)d_in[5];
    const float* W3 = (const float*)d_in[6];
    const float* b3 = (const float*)d_in[7];
    const float* ip = (const float*)d_in[8];
    const float* is = (const float*)d_in[9];
    const float* ic = (const float*)d_in[10];

    u16* w1h = (u16*)d_ws;            // 16 nt * 52 kf * 128
    u16* w1l = w1h + 16 * 52 * 128;
    u16* w2h = w1l + 16 * 52 * 128;   // 16 nt * 32 kf * 128
    u16* w2l = w2h + 16 * 32 * 128;
    u16* w3h = w2l + 16 * 32 * 128;   // 10 nt * 32 kf * 128
    u16* w3l = w3h + 10 * 32 * 128;

    prep_pack<<<dim3(4, 16), 256, 0, stream>>>(W1, w1h, w1l, 413, 256, 416);
    prep_pack<<<dim3(2, 16), 256, 0, stream>>>(W2, w2h, w2l, 256, 256, 256);
    prep_pack<<<dim3(2, 10), 256, 0, stream>>>(W3, w3h, w3l, 256, 157, 256);

    fused_head<<<NROWS / MT, 256, 0, stream>>>(x, w1h, w1l, w2h, w2l, w3h, w3l,
                                               b1, b2, b3, ip, is, ic, (float*)d_out);
}